// Round 1
// baseline (3205.779 us; speedup 1.0000x reference)
//
#include <hip/hip_runtime.h>
#include <math.h>
#include <stdint.h>

// Problem constants (fixed by setup_inputs)
#define S_DIM 128
#define B_DIM 256
#define L_DIM 512
#define K_DIM 8
#define T_IN  16
#define STEPS 103                      // 128 - 16 - (8 + 0 + 1)
#define DENOM (K_DIM * STEPS * B_DIM)  // 210944

// ---------------------------------------------------------------------------
// GEMM: C[i][m] = sum_l A[i][l] * W[m][l]
//   A: (STEPS*B, L) row-major  (context rows 16..118 flattened)
//   W: (L, L) row-major        (Wk[k], [m][l])
//   C: (STEPS*B, L) row-major  (pred for this k)
// BM=BN=128, BK=32, 256 threads, 8x8 micro-tile, transposed LDS staging.
// ---------------------------------------------------------------------------
__global__ __launch_bounds__(256, 2)
void gemm_pred(const float* __restrict__ A, const float* __restrict__ W,
               float* __restrict__ C) {
    __shared__ float As[32][128];   // [l][row]
    __shared__ float Ws[32][128];   // [l][m]
    const int bm = blockIdx.x, bn = blockIdx.y;
    const int t  = threadIdx.x;
    const int tx = t & 15, ty = t >> 4;
    const int lrow = t >> 3, lc4 = t & 7;
    const float* Ab = A + (size_t)bm * 128 * L_DIM;
    const float* Wb = W + (size_t)bn * 128 * L_DIM;

    float acc[8][8] = {};
    for (int lt = 0; lt < L_DIM; lt += 32) {
        #pragma unroll
        for (int i = 0; i < 4; i++) {
            const int row = lrow + 32 * i;
            const float4 av = *(const float4*)(Ab + (size_t)row * L_DIM + lt + lc4 * 4);
            const float4 wv = *(const float4*)(Wb + (size_t)row * L_DIM + lt + lc4 * 4);
            As[lc4*4+0][row] = av.x; As[lc4*4+1][row] = av.y;
            As[lc4*4+2][row] = av.z; As[lc4*4+3][row] = av.w;
            Ws[lc4*4+0][row] = wv.x; Ws[lc4*4+1][row] = wv.y;
            Ws[lc4*4+2][row] = wv.z; Ws[lc4*4+3][row] = wv.w;
        }
        __syncthreads();
        #pragma unroll 8
        for (int l = 0; l < 32; l++) {
            float a0[8], b0[8];
            *(float4*)&a0[0] = *(const float4*)&As[l][ty*4];
            *(float4*)&a0[4] = *(const float4*)&As[l][64 + ty*4];
            *(float4*)&b0[0] = *(const float4*)&Ws[l][tx*4];
            *(float4*)&b0[4] = *(const float4*)&Ws[l][64 + tx*4];
            #pragma unroll
            for (int i = 0; i < 8; i++)
                #pragma unroll
                for (int j = 0; j < 8; j++)
                    acc[i][j] = fmaf(a0[i], b0[j], acc[i][j]);
        }
        __syncthreads();
    }
    #pragma unroll
    for (int i = 0; i < 8; i++) {
        const int row = bm * 128 + ((i < 4) ? (ty*4 + i) : (64 + ty*4 + i - 4));
        float* Cr = C + (size_t)row * L_DIM + bn * 128;
        *(float4*)(Cr + tx*4)      = make_float4(acc[i][0], acc[i][1], acc[i][2], acc[i][3]);
        *(float4*)(Cr + 64 + tx*4) = make_float4(acc[i][4], acc[i][5], acc[i][6], acc[i][7]);
    }
}

// ---------------------------------------------------------------------------
// Fused sim + log-softmax stats for one k.
// grid (STEPS, 8). Block (s, bt): rows b = bt*32..bt*32+31, all 256 columns c.
//   sim[b][c] = sum_l enc[b][l] * pred[s*B + c][l],  enc = encoded_x[17+k+s]
// Row-wise lse (full c range in-block) -> diag logp accumulated (1 atomic/blk).
// Column argmax over b merged across bt-blocks via packed u64 atomicMax
// (ordered-float<<32 | (255-b) : value-major, first-index tie-break).
// ---------------------------------------------------------------------------
__global__ __launch_bounds__(256, 2)
void sim_phase(const float* __restrict__ encoded_x, const float* __restrict__ pred,
               const int k, unsigned long long* __restrict__ col_best,
               float* __restrict__ diag_accum) {
    __shared__ float Es[32][32];    // [l][row]
    __shared__ float Ps[256][33];   // [c][l]  (+1 pad: bank = (c+l)%32, conflict-free)
    __shared__ float sim[32][257];
    __shared__ float lse_s[32];
    const int s = blockIdx.x, bt = blockIdx.y;
    const int t = threadIdx.x;
    const int q = t & 31, rg = t >> 5;

    const float* enc = encoded_x + ((size_t)(T_IN + 1 + k + s) * B_DIM + bt * 32) * L_DIM;
    const float* pr  = pred + (size_t)s * B_DIM * L_DIM;

    float acc[4][8] = {};
    for (int lt = 0; lt < L_DIM; lt += 32) {
        {
            const int r = t >> 3, c4 = t & 7;
            const float4 ev = *(const float4*)(enc + (size_t)r * L_DIM + lt + c4 * 4);
            Es[c4*4+0][r] = ev.x; Es[c4*4+1][r] = ev.y;
            Es[c4*4+2][r] = ev.z; Es[c4*4+3][r] = ev.w;
            #pragma unroll
            for (int i = 0; i < 8; i++) {
                const int c = r + 32 * i;
                const float4 pv = *(const float4*)(pr + (size_t)c * L_DIM + lt + c4 * 4);
                Ps[c][c4*4+0] = pv.x; Ps[c][c4*4+1] = pv.y;
                Ps[c][c4*4+2] = pv.z; Ps[c][c4*4+3] = pv.w;
            }
        }
        __syncthreads();
        #pragma unroll 8
        for (int l = 0; l < 32; l++) {
            float a[4];
            *(float4*)a = *(const float4*)&Es[l][rg * 4];
            #pragma unroll
            for (int j = 0; j < 8; j++) {
                const float bv = Ps[q + 32 * j][l];
                #pragma unroll
                for (int i = 0; i < 4; i++)
                    acc[i][j] = fmaf(a[i], bv, acc[i][j]);
            }
        }
        __syncthreads();
    }
    #pragma unroll
    for (int i = 0; i < 4; i++)
        #pragma unroll
        for (int j = 0; j < 8; j++)
            sim[rg * 4 + i][q + 32 * j] = acc[i][j];
    __syncthreads();

    // row stats: 8 lanes per row (r = t>>3, lanes sub = t&7)
    {
        const int r = t >> 3, sub = t & 7;
        float m = -INFINITY;
        for (int c = sub; c < B_DIM; c += 8) m = fmaxf(m, sim[r][c]);
        #pragma unroll
        for (int off = 1; off < 8; off <<= 1) m = fmaxf(m, __shfl_xor(m, off, 64));
        float sum = 0.f;
        for (int c = sub; c < B_DIM; c += 8) sum += expf(sim[r][c] - m);
        #pragma unroll
        for (int off = 1; off < 8; off <<= 1) sum += __shfl_xor(sum, off, 64);
        if (sub == 0) lse_s[r] = m + logf(sum);
    }
    __syncthreads();

    // diag logp for this b-tile: sum_r (sim[r][bt*32+r] - lse[r]), one atomic/block
    if (t < 32) {
        float dv = sim[t][bt * 32 + t] - lse_s[t];
        #pragma unroll
        for (int off = 1; off < 32; off <<= 1) dv += __shfl_xor(dv, off, 64);
        if (t == 0) atomicAdd(diag_accum, dv);
    }

    // column argmax over this block's 32 rows; merge globally
    {
        float best = -INFINITY; int bestb = 0;
        #pragma unroll 4
        for (int r = 0; r < 32; r++) {
            const float v = sim[r][t] - lse_s[r];
            if (v > best) { best = v; bestb = bt * 32 + r; }   // strict > : first index wins
        }
        unsigned int fb = __float_as_uint(best);
        fb = (fb & 0x80000000u) ? ~fb : (fb | 0x80000000u);    // order-preserving map
        const unsigned long long packed =
            ((unsigned long long)fb << 32) | (unsigned long long)(255 - bestb);
        atomicMax(&col_best[((size_t)k * STEPS + s) * B_DIM + t], packed);
    }
}

__global__ void count_correct(const unsigned long long* __restrict__ col_best,
                              int* __restrict__ correct_accum) {
    __shared__ int red[256];
    const int t = threadIdx.x;
    int cnt = 0;
    for (int i = blockIdx.x * 256 + t; i < DENOM; i += gridDim.x * 256) {
        const int c = i & (B_DIM - 1);
        const int b = 255 - (int)(col_best[i] & 0xFFFFFFFFull);
        cnt += (b == c) ? 1 : 0;
    }
    red[t] = cnt;
    __syncthreads();
    for (int off = 128; off > 0; off >>= 1) {
        if (t < off) red[t] += red[t + off];
        __syncthreads();
    }
    if (t == 0) atomicAdd(correct_accum, red[0]);
}

__global__ void finalize(const int* __restrict__ correct_accum,
                         const float* __restrict__ diag_accum,
                         float* __restrict__ out) {
    const float denom = (float)DENOM;
    out[0] = (float)(*correct_accum) / denom;   // accuracy
    out[1] = -(*diag_accum) / denom;            // loss
}

extern "C" void kernel_launch(void* const* d_in, const int* in_sizes, int n_in,
                              void* d_out, int out_size, void* d_ws, size_t ws_size,
                              hipStream_t stream) {
    const float* encoded_x = (const float*)d_in[0];
    const float* context   = (const float*)d_in[1];
    const float* Wk        = (const float*)d_in[2];
    float* out = (float*)d_out;

    char* ws = (char*)d_ws;
    float* pred = (float*)ws;                                   // 26368*512 fp32 = 54 MB
    const size_t pred_bytes = (size_t)STEPS * B_DIM * L_DIM * sizeof(float);
    unsigned long long* col_best = (unsigned long long*)(ws + pred_bytes);
    const size_t cb_bytes = (size_t)DENOM * sizeof(unsigned long long);  // 1.69 MB
    float* diag_accum   = (float*)(ws + pred_bytes + cb_bytes);
    int*   correct_accum = (int*)(ws + pred_bytes + cb_bytes + sizeof(float));

    // zero col_best + both accumulators (ws is re-poisoned 0xAA before each launch)
    hipMemsetAsync(col_best, 0, cb_bytes + 16, stream);

    const float* A = context + (size_t)T_IN * B_DIM * L_DIM;    // ctx slice, contiguous
    const dim3 g1((STEPS * B_DIM) / 128, L_DIM / 128);          // (206, 4)
    const dim3 g2(STEPS, B_DIM / 32);                           // (103, 8)
    for (int k = 0; k < K_DIM; k++) {
        gemm_pred<<<g1, 256, 0, stream>>>(A, Wk + (size_t)k * L_DIM * L_DIM, pred);
        sim_phase<<<g2, 256, 0, stream>>>(encoded_x, pred, k, col_best, diag_accum);
    }
    count_correct<<<64, 256, 0, stream>>>(col_best, correct_accum);
    finalize<<<1, 1, 0, stream>>>(correct_accum, diag_accum, out);
}

// Round 2
// 991.311 us; speedup vs baseline: 3.2339x; 3.2339x over previous
//
#include <hip/hip_runtime.h>
#include <math.h>
#include <stdint.h>

// Problem constants (fixed by setup_inputs)
#define S_DIM 128
#define B_DIM 256
#define L_DIM 512
#define K_DIM 8
#define T_IN  16
#define STEPS 103                      // 128 - 16 - (8 + 0 + 1)
#define DENOM (K_DIM * STEPS * B_DIM)  // 210944

typedef __attribute__((ext_vector_type(8))) short short8;  // 8 bf16 = 4 VGPRs (MFMA A/B frag)
typedef __attribute__((ext_vector_type(4))) float f32x4;   // MFMA C/D frag

// round-to-nearest-even fp32 -> bf16
__device__ __forceinline__ short f2bf(float f) {
    unsigned u = __float_as_uint(f);
    u += 0x7FFFu + ((u >> 16) & 1u);
    return (short)(u >> 16);
}

// async global->LDS, 16B per lane; LDS dest = wave-uniform base + lane*16
__device__ __forceinline__ void load_lds16(const void* g, void* l) {
    __builtin_amdgcn_global_load_lds(
        (const __attribute__((address_space(1))) unsigned*)g,
        (__attribute__((address_space(3))) unsigned*)l, 16, 0, 0);
}

__global__ void convert_bf16(const float* __restrict__ in, short* __restrict__ out, int n4) {
    for (int i = blockIdx.x * blockDim.x + threadIdx.x; i < n4; i += gridDim.x * blockDim.x) {
        const float4 v = ((const float4*)in)[i];
        short4 o;
        o.x = f2bf(v.x); o.y = f2bf(v.y); o.z = f2bf(v.z); o.w = f2bf(v.w);
        ((short4*)out)[i] = o;
    }
}

// ---------------------------------------------------------------------------
// bf16 MFMA GEMM (NT): C[i][m] = sum_l A[i][l] * W[m][l], output bf16.
// A: (26368,512) bf16 row-major; W: (512,512) bf16 row-major; C: (26368,512) bf16.
// 128x128 tile, BK=32, 4 waves in 2x2, 4x4 16x16x32 frags per wave.
// Staging via global_load_lds(16B) with XOR chunk swizzle: lane loads global
// chunk (ko ^ ((row>>1)&3)) so the lane-ordered LDS layout de-conflicts the
// ds_read_b128 fragment reads (2 lanes/bank = free).
// ---------------------------------------------------------------------------
__global__ __launch_bounds__(256)
void gemm_bf16(const short* __restrict__ A, const short* __restrict__ W,
               short* __restrict__ C) {
    __shared__ short As[128 * 32];   // 8 KB, row-major [row][32], chunk-swizzled
    __shared__ short Bs[128 * 32];   // 8 KB
    const int bm = blockIdx.x, bn = blockIdx.y;
    const int t = threadIdx.x;
    const int w = t >> 6, lane = t & 63, quad = lane >> 4, l15 = lane & 15;
    const int wm = w & 1, wn = w >> 1;
    const int rloc = lane >> 2, ko = lane & 3;

    const short* Ab = A + (size_t)bm * 128 * L_DIM;
    const short* Wb = W + (size_t)bn * 128 * L_DIM;

    f32x4 acc[4][4] = {};

    for (int kt = 0; kt < L_DIM; kt += 32) {
        #pragma unroll
        for (int j = 0; j < 2; j++) {                 // each wave stages 32 rows of A and B
            const int rb = w * 32 + j * 16;
            const int row = rb + rloc;
            const int ch = ko ^ ((row >> 1) & 3);
            load_lds16(Ab + (size_t)row * L_DIM + kt + ch * 8, &As[rb * 32]);
            load_lds16(Wb + (size_t)row * L_DIM + kt + ch * 8, &Bs[rb * 32]);
        }
        __syncthreads();                              // drains vmcnt (compiler-inserted)
        short8 a[4], b[4];
        #pragma unroll
        for (int i = 0; i < 4; i++) {
            const int m = wm * 64 + i * 16 + l15;
            a[i] = *(const short8*)&As[m * 32 + (quad ^ ((m >> 1) & 3)) * 8];
            const int n = wn * 64 + i * 16 + l15;
            b[i] = *(const short8*)&Bs[n * 32 + (quad ^ ((n >> 1) & 3)) * 8];
        }
        #pragma unroll
        for (int i = 0; i < 4; i++)
            #pragma unroll
            for (int j = 0; j < 4; j++)
                acc[i][j] = __builtin_amdgcn_mfma_f32_16x16x32_bf16(a[i], b[j], acc[i][j], 0, 0, 0);
        __syncthreads();
    }
    // C/D layout: col = lane&15, row = quad*4 + reg  [m89/m91-verified]
    #pragma unroll
    for (int i = 0; i < 4; i++) {
        #pragma unroll
        for (int r = 0; r < 4; r++) {
            const int row = bm * 128 + wm * 64 + i * 16 + quad * 4 + r;
            short* Cr = C + (size_t)row * L_DIM + bn * 128 + wn * 64 + l15;
            #pragma unroll
            for (int j = 0; j < 4; j++)
                Cr[j * 16] = f2bf(acc[i][j][r]);
        }
    }
}

// ---------------------------------------------------------------------------
// Fused sim + log-softmax stats for one k (MFMA K-loop).
// grid (STEPS, 8). Block (s, bt): rows b = bt*32..+31, all 256 columns c.
//   sim[b][c] = sum_l enc[b][l] * pred[s*256 + c][l]  (NT, bf16 MFMA, fp32 acc)
// Wave w covers cols [w*64, w*64+64): 2 (m) x 4 (n) frags.
// Epilogue identical to the round-1-verified fp32 version.
// ---------------------------------------------------------------------------
__global__ __launch_bounds__(256)
void sim_phase(const float* __restrict__ encoded_x, const short* __restrict__ pred,
               const int k, unsigned long long* __restrict__ col_best,
               float* __restrict__ diag_accum) {
    __shared__ union {
        struct { short es[32 * 40]; short ps[256 * 32]; } st;  // 2560 + 16384 B
        float sim[32][257];                                    // 32896 B
    } u;
    __shared__ float lse_s[32];
    const int s = blockIdx.x, bt = blockIdx.y;
    const int t = threadIdx.x;
    const int w = t >> 6, lane = t & 63, quad = lane >> 4, l15 = lane & 15;
    const int rloc = lane >> 2, ko = lane & 3;

    const float* encb = encoded_x + ((size_t)(T_IN + 1 + k + s) * B_DIM + bt * 32) * L_DIM;
    const short* prb  = pred + (size_t)s * B_DIM * L_DIM;

    f32x4 acc[2][4] = {};
    const int er = t >> 3, ec = (t & 7) * 4;

    for (int kt = 0; kt < L_DIM; kt += 32) {
        {   // Es: manual fp32->bf16 stage, stride 40 shorts (80B, 16B-multiple)
            const float4 v = *(const float4*)(encb + (size_t)er * L_DIM + kt + ec);
            short4 o; o.x = f2bf(v.x); o.y = f2bf(v.y); o.z = f2bf(v.z); o.w = f2bf(v.w);
            *(short4*)&u.st.es[er * 40 + ec] = o;
        }
        #pragma unroll
        for (int j = 0; j < 4; j++) {                 // Ps: wave w stages rows w*64..+63
            const int rb = w * 64 + j * 16;
            const int row = rb + rloc;
            const int ch = ko ^ ((row >> 1) & 3);
            load_lds16(prb + (size_t)row * L_DIM + kt + ch * 8, &u.st.ps[rb * 32]);
        }
        __syncthreads();
        short8 a[2], b[4];
        #pragma unroll
        for (int i = 0; i < 2; i++)
            a[i] = *(const short8*)&u.st.es[(i * 16 + l15) * 40 + quad * 8];
        #pragma unroll
        for (int j = 0; j < 4; j++) {
            const int n = w * 64 + j * 16 + l15;
            b[j] = *(const short8*)&u.st.ps[n * 32 + (quad ^ ((n >> 1) & 3)) * 8];
        }
        #pragma unroll
        for (int i = 0; i < 2; i++)
            #pragma unroll
            for (int j = 0; j < 4; j++)
                acc[i][j] = __builtin_amdgcn_mfma_f32_16x16x32_bf16(a[i], b[j], acc[i][j], 0, 0, 0);
        __syncthreads();
    }
    // spill accumulators to sim LDS tile (aliases staging; last barrier protects)
    #pragma unroll
    for (int i = 0; i < 2; i++)
        #pragma unroll
        for (int j = 0; j < 4; j++)
            #pragma unroll
            for (int r = 0; r < 4; r++)
                u.sim[i * 16 + quad * 4 + r][w * 64 + j * 16 + l15] = acc[i][j][r];
    __syncthreads();

    // row stats: 8 lanes per row
    {
        const int r = t >> 3, sub = t & 7;
        float m = -INFINITY;
        for (int c = sub; c < B_DIM; c += 8) m = fmaxf(m, u.sim[r][c]);
        #pragma unroll
        for (int off = 1; off < 8; off <<= 1) m = fmaxf(m, __shfl_xor(m, off, 64));
        float sum = 0.f;
        for (int c = sub; c < B_DIM; c += 8) sum += expf(u.sim[r][c] - m);
        #pragma unroll
        for (int off = 1; off < 8; off <<= 1) sum += __shfl_xor(sum, off, 64);
        if (sub == 0) lse_s[r] = m + logf(sum);
    }
    __syncthreads();

    // diag logp for this b-tile (one atomic per block)
    if (t < 32) {
        float dv = u.sim[t][bt * 32 + t] - lse_s[t];
        #pragma unroll
        for (int off = 1; off < 32; off <<= 1) dv += __shfl_xor(dv, off, 64);
        if (t == 0) atomicAdd(diag_accum, dv);
    }

    // column argmax over this block's 32 rows; merge globally
    {
        float best = -INFINITY; int bestb = 0;
        #pragma unroll 4
        for (int r = 0; r < 32; r++) {
            const float v = u.sim[r][t] - lse_s[r];
            if (v > best) { best = v; bestb = bt * 32 + r; }   // strict > : first index wins
        }
        unsigned int fb = __float_as_uint(best);
        fb = (fb & 0x80000000u) ? ~fb : (fb | 0x80000000u);    // order-preserving map
        const unsigned long long packed =
            ((unsigned long long)fb << 32) | (unsigned long long)(255 - bestb);
        atomicMax(&col_best[((size_t)k * STEPS + s) * B_DIM + t], packed);
    }
}

__global__ void count_correct(const unsigned long long* __restrict__ col_best,
                              int* __restrict__ correct_accum) {
    __shared__ int red[256];
    const int t = threadIdx.x;
    int cnt = 0;
    for (int i = blockIdx.x * 256 + t; i < DENOM; i += gridDim.x * 256) {
        const int c = i & (B_DIM - 1);
        const int b = 255 - (int)(col_best[i] & 0xFFFFFFFFull);
        cnt += (b == c) ? 1 : 0;
    }
    red[t] = cnt;
    __syncthreads();
    for (int off = 128; off > 0; off >>= 1) {
        if (t < off) red[t] += red[t + off];
        __syncthreads();
    }
    if (t == 0) atomicAdd(correct_accum, red[0]);
}

__global__ void finalize(const int* __restrict__ correct_accum,
                         const float* __restrict__ diag_accum,
                         float* __restrict__ out) {
    const float denom = (float)DENOM;
    out[0] = (float)(*correct_accum) / denom;   // accuracy
    out[1] = -(*diag_accum) / denom;            // loss
}

extern "C" void kernel_launch(void* const* d_in, const int* in_sizes, int n_in,
                              void* d_out, int out_size, void* d_ws, size_t ws_size,
                              hipStream_t stream) {
    const float* encoded_x = (const float*)d_in[0];
    const float* context   = (const float*)d_in[1];
    const float* Wk        = (const float*)d_in[2];
    float* out = (float*)d_out;

    char* ws = (char*)d_ws;
    const size_t pred_elems = (size_t)STEPS * B_DIM * L_DIM;   // 13,500,416
    short* predbf = (short*)ws;                                 // 27.0 MB
    short* Abf    = (short*)(ws + pred_elems * 2);              // 27.0 MB
    short* Wkbf   = (short*)(ws + pred_elems * 4);              // 4.2 MB
    const size_t off = pred_elems * 4 + (size_t)K_DIM * L_DIM * L_DIM * 2;
    unsigned long long* col_best = (unsigned long long*)(ws + off);  // 1.69 MB
    float* diag_accum    = (float*)(ws + off + (size_t)DENOM * 8);
    int*   correct_accum = (int*)  (ws + off + (size_t)DENOM * 8 + 4);

    hipMemsetAsync(col_best, 0, (size_t)DENOM * 8 + 16, stream);

    convert_bf16<<<2048, 256, 0, stream>>>(context + (size_t)T_IN * B_DIM * L_DIM,
                                           Abf, (int)(pred_elems / 4));
    convert_bf16<<<512, 256, 0, stream>>>(Wk, Wkbf, K_DIM * L_DIM * L_DIM / 4);

    const dim3 g1((STEPS * B_DIM) / 128, L_DIM / 128);          // (206, 4)
    const dim3 g2(STEPS, B_DIM / 32);                           // (103, 8)
    for (int k = 0; k < K_DIM; k++) {
        gemm_bf16<<<g1, 256, 0, stream>>>(Abf, Wkbf + (size_t)k * L_DIM * L_DIM, predbf);
        sim_phase<<<g2, 256, 0, stream>>>(encoded_x, predbf, k, col_best, diag_accum);
    }
    count_correct<<<64, 256, 0, stream>>>(col_best, correct_accum);
    finalize<<<1, 1, 0, stream>>>(correct_accum, diag_accum, out);
}